// Round 5
// baseline (3137.205 us; speedup 1.0000x reference)
//
#include <hip/hip_runtime.h>

#define NBLK 256
#define ROWS 18

__device__ __forceinline__ float dot4(float4 a, float4 b){
  return fmaf(a.x,b.x, fmaf(a.y,b.y, fmaf(a.z,b.z, a.w*b.w)));
}
__device__ __forceinline__ void fma4(float& acc, float4 w, float4 a){
  acc = fmaf(w.x,a.x, fmaf(w.y,a.y, fmaf(w.z,a.z, fmaf(w.w,a.w, acc))));
}
__device__ __forceinline__ float wred(float v){
  #pragma unroll
  for (int m = 32; m >= 1; m >>= 1) v += __shfl_xor(v, m);
  return v;
}

// Device-wide barrier: one atomic + spin per block, full fence pair for
// cross-XCD visibility of plain stores (release wbl2 / acquire inv).
__device__ __forceinline__ void gbar(unsigned* p){
  __syncthreads();
  if (threadIdx.x == 0) {
    __threadfence();   // release
    __hip_atomic_fetch_add(p, 1u, __ATOMIC_RELAXED, __HIP_MEMORY_SCOPE_AGENT);
    while (__hip_atomic_load(p, __ATOMIC_RELAXED, __HIP_MEMORY_SCOPE_AGENT) < NBLK)
      __builtin_amdgcn_s_sleep(2);
    __threadfence();   // acquire
  }
  __syncthreads();
}

__global__ __launch_bounds__(512, 1)
void vox_persist(const int* __restrict__ step, const float* __restrict__ random_,
                 const float* __restrict__ dit_h, const float* __restrict__ feat,
                 const float* __restrict__ cfg, const float* __restrict__ cfgm,
                 const float* __restrict__ t_emb, const float* __restrict__ dt,
                 const float* __restrict__ in_w, const float* __restrict__ in_b,
                 const float* __restrict__ qkv_w, const float* __restrict__ qkv_b,
                 const float* __restrict__ o_w, const float* __restrict__ gu_w,
                 const float* __restrict__ dn_w, const float* __restrict__ op_w,
                 const float* __restrict__ op_b,
                 unsigned* __restrict__ bars,
                 float* __restrict__ hs, float* __restrict__ qkvb,
                 float* __restrict__ gub, float* __restrict__ dout)
{
  __shared__ float sact[ROWS * 1024];
  __shared__ float sscale[ROWS];
  __shared__ float sA[8], sB[8];

  const int b    = blockIdx.x;
  const int tid  = threadIdx.x;
  const int w    = tid >> 6;
  const int lane = tid & 63;
  int bi = 0;

  const float ropeInv = powf(10000.f, -(float)(lane & 31) * (1.f / 32.f));

  float4 wbufA[8], wbufB[8];

  // ---------------- prep: hs[18][1024] ----------------
  if (b < 2) {
    const int c  = b * 512 + tid;
    const int st = step[0];
    const float tv = t_emb[(size_t)st * 1024 + c];
    hs[0 * 1024 + c] = dit_h[c] + tv;
    hs[9 * 1024 + c] = tv;
    #pragma unroll
    for (int p = 0; p < 4; p++) {
      hs[(1 + p)  * 1024 + c] = feat[(size_t)(p)     * 1024 + c];
      hs[(10 + p) * 1024 + c] = feat[(size_t)(4 + p) * 1024 + c];
    }
    #pragma unroll
    for (int p = 0; p < 4; p++) {
      float a = in_b[c];
      #pragma unroll
      for (int q4 = 0; q4 < 16; q4++) {
        float4 wv = *(const float4*)&in_w[(size_t)c * 64 + q4 * 4];
        float4 rv = *(const float4*)&random_[p * 64 + q4 * 4];
        a += dot4(wv, rv);
      }
      hs[(5 + p)  * 1024 + c] = a;
      hs[(14 + p) * 1024 + c] = a;
    }
  }

  // phase-static block mappings
  const int cbq = 12 * b;                   // QKV col base (waves 0-5, 2 cols)
  const int cg  = b & 63, ky = b >> 6;      // O / DOWN col-group & K-split
  const int cbo = 16 * cg;
  const int cbg = 16 * b;                   // GU col base (8 waves x 2 cols)
  const int cbd = 16 * cg;

  auto stage = [&](const float* src, int stride, int koff) {
    #pragma unroll
    for (int t = 0; t < 9; t++) {
      const int t4 = t * 512 + tid;
      const int r  = t4 >> 8;
      const int k4 = (t4 & 255) * 4;
      *(float4*)&sact[r * 1024 + k4] = *(const float4*)&src[(size_t)r * stride + koff + k4];
    }
  };

  // prefetch QKV layer-0 weights (waves 0-5: 2 cols x 4 chunks)
  if (w < 6) {
    #pragma unroll
    for (int c = 0; c < 2; c++)
      #pragma unroll
      for (int ch = 0; ch < 4; ch++)
        wbufA[c * 4 + ch] = *(const float4*)&qkv_w[(size_t)(cbq + 2 * w + c) * 1024 + ch * 256 + 4 * lane];
  }
  gbar(&bars[(bi++) * 16]);

  for (int l = 0; l < 8; l++) {
    const float* qb = qkv_b + (size_t)l * 3072;
    const float* ow = o_w   + (size_t)l * 1024 * 1024;
    const float* gw = gu_w  + (size_t)l * 8192 * 1024;
    const float* dw = dn_w  + (size_t)l * 1024 * 4096;

    // ============ QKV: qkvb = rms(hs) @ qw^T + qb ============
    {
      stage(hs, 1024, 0);
      __syncthreads();
      if (w >= 6) {                 // waves 6,7: rms of 9 rows each
        #pragma unroll
        for (int t = 0; t < 9; t++) {
          const int r = (w - 6) * 9 + t;
          float ss = 0.f;
          #pragma unroll
          for (int q = 0; q < 4; q++) {
            float4 a = *(const float4*)&sact[r * 1024 + q * 256 + 4 * lane];
            ss += dot4(a, a);
          }
          ss = wred(ss);
          if (lane == 0) sscale[r] = rsqrtf(ss);
        }
      }
      float acc[2][ROWS];
      if (w < 6) {
        #pragma unroll
        for (int c = 0; c < 2; c++)
          #pragma unroll
          for (int r = 0; r < ROWS; r++) acc[c][r] = 0.f;
        #pragma unroll
        for (int ch = 0; ch < 4; ch++)
          #pragma unroll
          for (int r = 0; r < ROWS; r++) {
            float4 a = *(const float4*)&sact[r * 1024 + ch * 256 + 4 * lane];
            fma4(acc[0][r], wbufA[ch], a);
            fma4(acc[1][r], wbufA[4 + ch], a);
          }
      }
      __syncthreads();              // sscale ready
      if (w < 6) {
        #pragma unroll
        for (int c = 0; c < 2; c++)
          #pragma unroll
          for (int r = 0; r < ROWS; r++) {
            float v = wred(acc[c][r]);
            if (lane == 0) {
              const int col = cbq + 2 * w + c;
              qkvb[r * 3072 + col] = v * sscale[r] + qb[col];
            }
          }
      }
    }
    // prefetch O weights (2 cols x 1 chunk of the ky K=256 slice)
    #pragma unroll
    for (int c = 0; c < 2; c++)
      wbufA[c] = *(const float4*)&ow[(size_t)(cbo + 2 * w + c) * 1024 + ky * 256 + 4 * lane];
    gbar(&bars[(bi++) * 16]);

    // ============ attn (4 heads in-block) + O K-split, atomic += hs ============
    {
      const int bb = w >> 2, hw = w & 3, h = 4 * ky + hw;
      float q[9], k[9], v[9];
      #pragma unroll
      for (int i = 0; i < 9; i++) {
        const float* base = qkvb + (size_t)(bb * 9 + i) * 3072;
        q[i] = base[h * 64 + lane];
        k[i] = base[1024 + h * 64 + lane];
        v[i] = base[2048 + h * 64 + lane];
      }
      #pragma unroll
      for (int i = 0; i < 9; i++) {
        const float ang = (float)i * ropeInv;
        float sn, cs;
        __sincosf(ang, &sn, &cs);
        const float sgn = (lane < 32) ? -sn : sn;
        const float rq = __shfl_xor(q[i], 32);
        const float rk = __shfl_xor(k[i], 32);
        q[i] = q[i] * cs + rq * sgn;
        k[i] = k[i] * cs + rk * sgn;
      }
      #pragma unroll
      for (int i = 0; i < 9; i++) {
        float sc[9];
        #pragma unroll
        for (int jj = 0; jj < 9; jj++) sc[jj] = wred(q[i] * k[jj]);
        float mx = sc[0];
        #pragma unroll
        for (int jj = 1; jj < 9; jj++) mx = fmaxf(mx, sc[jj]);
        float den = 0.f;
        #pragma unroll
        for (int jj = 0; jj < 9; jj++) { sc[jj] = __expf(sc[jj] - mx); den += sc[jj]; }
        float o = 0.f;
        #pragma unroll
        for (int jj = 0; jj < 9; jj++) o += sc[jj] * v[jj];
        sact[(bb * 9 + i) * 256 + hw * 64 + lane] = o / den;
      }
      __syncthreads();
      float acc[2][ROWS];
      #pragma unroll
      for (int c = 0; c < 2; c++)
        #pragma unroll
        for (int r = 0; r < ROWS; r++) acc[c][r] = 0.f;
      #pragma unroll
      for (int r = 0; r < ROWS; r++) {
        float4 a = *(const float4*)&sact[r * 256 + 4 * lane];
        fma4(acc[0][r], wbufA[0], a);
        fma4(acc[1][r], wbufA[1], a);
      }
      #pragma unroll
      for (int c = 0; c < 2; c++)
        #pragma unroll
        for (int r = 0; r < ROWS; r++) {
          float v2 = wred(acc[c][r]);
          if (lane == 0) atomicAdd(&hs[r * 1024 + cbo + 2 * w + c], v2);
        }
    }
    // prefetch GU gate weights only (2 cols x 4 chunks)
    {
      const int c0 = cbg + 2 * w;
      #pragma unroll
      for (int j = 0; j < 2; j++)
        #pragma unroll
        for (int ch = 0; ch < 4; ch++)
          wbufA[j * 4 + ch] = *(const float4*)&gw[(size_t)(c0 + j) * 1024 + ch * 256 + 4 * lane];
    }
    gbar(&bars[(bi++) * 16]);

    // ============ gate_up + silu -> gub (gate then up, sequential) ============
    {
      // issue up-weight loads now; latency hides under stage+rms+gate-FMA
      const int c0 = cbg + 2 * w;
      #pragma unroll
      for (int j = 0; j < 2; j++)
        #pragma unroll
        for (int ch = 0; ch < 4; ch++)
          wbufB[j * 4 + ch] = *(const float4*)&gw[(size_t)(4096 + c0 + j) * 1024 + ch * 256 + 4 * lane];

      stage(hs, 1024, 0);
      __syncthreads();
      #pragma unroll
      for (int t = 0; t < 3; t++) {
        const int r = w + 8 * t;
        if (r < ROWS) {
          float ss = 0.f;
          #pragma unroll
          for (int q = 0; q < 4; q++) {
            float4 a = *(const float4*)&sact[r * 1024 + q * 256 + 4 * lane];
            ss += dot4(a, a);
          }
          ss = wred(ss);
          if (lane == 0) sscale[r] = rsqrtf(ss);
        }
      }
      __syncthreads();

      float acc[2][ROWS];
      #pragma unroll
      for (int c = 0; c < 2; c++)
        #pragma unroll
        for (int r = 0; r < ROWS; r++) acc[c][r] = 0.f;
      #pragma unroll
      for (int ch = 0; ch < 4; ch++)
        #pragma unroll
        for (int r = 0; r < ROWS; r++) {
          float4 a = *(const float4*)&sact[r * 1024 + ch * 256 + 4 * lane];
          fma4(acc[0][r], wbufA[ch], a);
          fma4(acc[1][r], wbufA[4 + ch], a);
        }
      float gp[2][ROWS];
      #pragma unroll
      for (int c = 0; c < 2; c++)
        #pragma unroll
        for (int r = 0; r < ROWS; r++) gp[c][r] = wred(acc[c][r]);

      #pragma unroll
      for (int c = 0; c < 2; c++)
        #pragma unroll
        for (int r = 0; r < ROWS; r++) acc[c][r] = 0.f;
      #pragma unroll
      for (int ch = 0; ch < 4; ch++)
        #pragma unroll
        for (int r = 0; r < ROWS; r++) {
          float4 a = *(const float4*)&sact[r * 1024 + ch * 256 + 4 * lane];
          fma4(acc[0][r], wbufB[ch], a);
          fma4(acc[1][r], wbufB[4 + ch], a);
        }
      #pragma unroll
      for (int c = 0; c < 2; c++)
        #pragma unroll
        for (int r = 0; r < ROWS; r++) {
          float u = wred(acc[c][r]);
          if (lane == 0) {
            const float s = sscale[r];
            const float g = gp[c][r] * s;
            u *= s;
            gub[r * 4096 + c0 + c] = g / (1.f + __expf(-g)) * u;
          }
        }
    }
    // prefetch DOWN weights: 2 cols x 4 chunks of the ky K=1024 slice
    #pragma unroll
    for (int c = 0; c < 2; c++)
      #pragma unroll
      for (int ch = 0; ch < 4; ch++)
        wbufA[c * 4 + ch] = *(const float4*)&dw[(size_t)(cbd + 2 * w + c) * 4096 + ky * 1024 + ch * 256 + 4 * lane];
    gbar(&bars[(bi++) * 16]);

    // ============ down K-split, atomic += hs ============
    {
      stage(gub, 4096, ky * 1024);
      __syncthreads();
      float acc[2][ROWS];
      #pragma unroll
      for (int c = 0; c < 2; c++)
        #pragma unroll
        for (int r = 0; r < ROWS; r++) acc[c][r] = 0.f;
      #pragma unroll
      for (int ch = 0; ch < 4; ch++)
        #pragma unroll
        for (int r = 0; r < ROWS; r++) {
          float4 a = *(const float4*)&sact[r * 1024 + ch * 256 + 4 * lane];
          fma4(acc[0][r], wbufA[ch], a);
          fma4(acc[1][r], wbufA[4 + ch], a);
        }
      #pragma unroll
      for (int c = 0; c < 2; c++)
        #pragma unroll
        for (int r = 0; r < ROWS; r++) {
          float v2 = wred(acc[c][r]);
          if (lane == 0) atomicAdd(&hs[r * 1024 + cbd + 2 * w + c], v2);
        }
    }
    // prefetch next layer's QKV weights
    if (l < 7) {
      const float* qwn = qkv_w + (size_t)(l + 1) * 3072 * 1024;
      if (w < 6) {
        #pragma unroll
        for (int c = 0; c < 2; c++)
          #pragma unroll
          for (int ch = 0; ch < 4; ch++)
            wbufA[c * 4 + ch] = *(const float4*)&qwn[(size_t)(cbq + 2 * w + c) * 1024 + ch * 256 + 4 * lane];
      }
    }
    gbar(&bars[(bi++) * 16]);
  }

  // ============ out_proj + CFG combine (block 0) ============
  if (b == 0) {
    for (int t4 = tid; t4 < 2048; t4 += 512) {
      const int r8 = t4 / 256;
      const int k4 = (t4 % 256) * 4;
      const int row = (r8 >> 2) * 9 + 5 + (r8 & 3);
      *(float4*)&sact[r8 * 1024 + k4] = *(const float4*)&hs[(size_t)row * 1024 + k4];
    }
    __syncthreads();
    {
      float ss = 0.f;
      #pragma unroll
      for (int qq = 0; qq < 4; qq++) {
        float4 a = *(const float4*)&sact[w * 1024 + 4 * lane + 256 * qq];
        ss += dot4(a, a);
      }
      ss = wred(ss);
      if (lane == 0) sA[w] = rsqrtf(ss);
    }
    __syncthreads();
    float outv;
    {
      const int r8 = tid & 7;
      const int c  = tid >> 3;
      float a0 = 0.f, a1 = 0.f;
      #pragma unroll 4
      for (int k4 = 0; k4 < 128; k4++) {
        a0 += dot4(*(const float4*)&sact[r8 * 1024 + 8 * k4],
                   *(const float4*)&op_w[(size_t)c * 1024 + 8 * k4]);
        a1 += dot4(*(const float4*)&sact[r8 * 1024 + 8 * k4 + 4],
                   *(const float4*)&op_w[(size_t)c * 1024 + 8 * k4 + 4]);
      }
      outv = (a0 + a1) * sA[r8] + op_b[c];
    }
    __syncthreads();
    {
      const int r8 = tid & 7;
      const int c  = tid >> 3;
      sact[r8 * 64 + c] = outv;
    }
    __syncthreads();
    float pos = 0.f, neg = 0.f, dd = 0.f, sq = 0.f;
    if (tid < 256) {
      pos = sact[tid]; neg = sact[256 + tid];
      dd = pos * neg; sq = neg * neg;
    }
    dd = wred(dd); sq = wred(sq);
    if (lane == 0) { sA[w] = dd; sB[w] = sq; }
    __syncthreads();
    if (tid < 256) {
      float dot = 0.f, sqs = 0.f;
      #pragma unroll
      for (int jj = 0; jj < 8; jj++) { dot += sA[jj]; sqs += sB[jj]; }
      const float guided = cfg[0] * pos + cfgm[0] * (dot / sqs) * neg;
      dout[tid] = random_[tid] + guided * dt[step[0]];
    }
  }
}

extern "C" void kernel_launch(void* const* d_in, const int* in_sizes, int n_in,
                              void* d_out, int out_size, void* d_ws, size_t ws_size,
                              hipStream_t stream)
{
  const int*   step    = (const int*)  d_in[0];
  const float* random_ = (const float*)d_in[1];
  const float* dit_h   = (const float*)d_in[2];
  const float* feat    = (const float*)d_in[3];
  const float* cfg     = (const float*)d_in[4];
  const float* cfgm    = (const float*)d_in[5];
  const float* t_emb   = (const float*)d_in[6];
  const float* dt      = (const float*)d_in[7];
  const float* in_w    = (const float*)d_in[8];
  const float* in_b    = (const float*)d_in[9];
  const float* qkv_w   = (const float*)d_in[10];
  const float* qkv_b   = (const float*)d_in[11];
  const float* o_w     = (const float*)d_in[12];
  const float* gu_w    = (const float*)d_in[13];
  const float* dn_w    = (const float*)d_in[14];
  const float* op_w    = (const float*)d_in[15];
  const float* op_b    = (const float*)d_in[16];

  unsigned* bars = (unsigned*)d_ws;                       // [0, 4096)
  float* hs   = (float*)((char*)d_ws + 4096);             // 18*1024
  float* qkvb = hs + ROWS * 1024;                         // 18*3072
  float* gub  = qkvb + ROWS * 3072;                       // 18*4096
  float* dout = (float*)d_out;

  hipMemsetAsync(d_ws, 0, 4096, stream);

  void* args[] = {
    (void*)&step, (void*)&random_, (void*)&dit_h, (void*)&feat, (void*)&cfg,
    (void*)&cfgm, (void*)&t_emb, (void*)&dt, (void*)&in_w, (void*)&in_b,
    (void*)&qkv_w, (void*)&qkv_b, (void*)&o_w, (void*)&gu_w, (void*)&dn_w,
    (void*)&op_w, (void*)&op_b, (void*)&bars,
    (void*)&hs, (void*)&qkvb, (void*)&gub, (void*)&dout
  };
  hipLaunchCooperativeKernel((void*)vox_persist, dim3(NBLK), dim3(512),
                             args, 0, stream);
}

// Round 6
// 2656.258 us; speedup vs baseline: 1.1811x; 1.1811x over previous
//
#include <hip/hip_runtime.h>

#define NBLK 256
#define ROWS 18

__device__ __forceinline__ float dot4(float4 a, float4 b){
  return fmaf(a.x,b.x, fmaf(a.y,b.y, fmaf(a.z,b.z, a.w*b.w)));
}
__device__ __forceinline__ void fma4(float& acc, float4 w, float4 a){
  acc = fmaf(w.x,a.x, fmaf(w.y,a.y, fmaf(w.z,a.z, fmaf(w.w,a.w, acc))));
}
__device__ __forceinline__ float wred(float v){
  #pragma unroll
  for (int m = 32; m >= 1; m >>= 1) v += __shfl_xor(v, m);
  return v;
}

// Device-wide barrier (proven correct R4/R5): one atomic + spin per block,
// full fence pair for cross-XCD visibility of plain stores.
__device__ __forceinline__ void gbar(unsigned* p){
  __syncthreads();
  if (threadIdx.x == 0) {
    __threadfence();   // release
    __hip_atomic_fetch_add(p, 1u, __ATOMIC_RELAXED, __HIP_MEMORY_SCOPE_AGENT);
    while (__hip_atomic_load(p, __ATOMIC_RELAXED, __HIP_MEMORY_SCOPE_AGENT) < NBLK)
      __builtin_amdgcn_s_sleep(2);
    __threadfence();   // acquire
  }
  __syncthreads();
}

__global__ __launch_bounds__(512, 1)
void vox_persist(const int* __restrict__ step, const float* __restrict__ random_,
                 const float* __restrict__ dit_h, const float* __restrict__ feat,
                 const float* __restrict__ cfg, const float* __restrict__ cfgm,
                 const float* __restrict__ t_emb, const float* __restrict__ dt,
                 const float* __restrict__ in_w, const float* __restrict__ in_b,
                 const float* __restrict__ qkv_w, const float* __restrict__ qkv_b,
                 const float* __restrict__ o_w, const float* __restrict__ gu_w,
                 const float* __restrict__ dn_w, const float* __restrict__ op_w,
                 const float* __restrict__ op_b,
                 unsigned* __restrict__ bars,
                 float* __restrict__ hs, float* __restrict__ qkvb,
                 float* __restrict__ gub, float* __restrict__ dout)
{
  __shared__ float sact[ROWS * 1024];
  __shared__ float sredG[16 * ROWS];
  __shared__ float sscale[ROWS];
  __shared__ float sA[8], sB[8];

  const int b    = blockIdx.x;
  const int tid  = threadIdx.x;
  const int w    = tid >> 6;
  const int lane = tid & 63;
  int bi = 0;

  // ---------------- prep: hs[18][1024] ----------------
  if (b < 2) {
    const int c  = b * 512 + tid;
    const int st = step[0];
    const float tv = t_emb[(size_t)st * 1024 + c];
    hs[0 * 1024 + c] = dit_h[c] + tv;
    hs[9 * 1024 + c] = tv;
    #pragma unroll
    for (int p = 0; p < 4; p++) {
      hs[(1 + p)  * 1024 + c] = feat[(size_t)(p)     * 1024 + c];
      hs[(10 + p) * 1024 + c] = feat[(size_t)(4 + p) * 1024 + c];
    }
    #pragma unroll
    for (int p = 0; p < 4; p++) {
      float a = in_b[c];
      #pragma unroll
      for (int q4 = 0; q4 < 16; q4++) {
        float4 wv = *(const float4*)&in_w[(size_t)c * 64 + q4 * 4];
        float4 rv = *(const float4*)&random_[p * 64 + q4 * 4];
        a += dot4(wv, rv);
      }
      hs[(5 + p)  * 1024 + c] = a;
      hs[(14 + p) * 1024 + c] = a;
    }
  }

  // phase-static block mappings
  const int cbq = 12 * b;                   // QKV col base (waves 0-5, 2 cols)
  const int cg  = b & 63, ky = b >> 6;      // O / DOWN col-group & K-split
  const int cbo = 16 * cg;
  const int cbg = 16 * b;                   // GU col base (8 waves x 2 cols)
  const int cbd = 16 * cg;

  auto stage = [&](const float* src, int stride, int koff) {
    #pragma unroll 3
    for (int t = 0; t < 9; t++) {
      const int t4 = t * 512 + tid;
      const int r  = t4 >> 8;
      const int k4 = (t4 & 255) * 4;
      *(float4*)&sact[r * 1024 + k4] = *(const float4*)&src[(size_t)r * stride + koff + k4];
    }
  };

  gbar(&bars[(bi++) * 16]);

  for (int l = 0; l < 8; l++) {
    const float* qw = qkv_w + (size_t)l * 3072 * 1024;
    const float* qb = qkv_b + (size_t)l * 3072;
    const float* ow = o_w   + (size_t)l * 1024 * 1024;
    const float* gw = gu_w  + (size_t)l * 8192 * 1024;
    const float* dw = dn_w  + (size_t)l * 1024 * 4096;

    // ============ QKV: qkvb = rms(hs) @ qw^T + qb ============
    {
      float4 wbuf[8];
      if (w < 6) {
        #pragma unroll
        for (int c = 0; c < 2; c++)
          #pragma unroll
          for (int ch = 0; ch < 4; ch++)
            wbuf[c * 4 + ch] = *(const float4*)&qw[(size_t)(cbq + 2 * w + c) * 1024 + ch * 256 + 4 * lane];
      }
      stage(hs, 1024, 0);
      __syncthreads();
      if (w >= 6) {                 // waves 6,7: rms of 9 rows each
        #pragma unroll
        for (int t = 0; t < 9; t++) {
          const int r = (w - 6) * 9 + t;
          float ss = 0.f;
          #pragma unroll
          for (int q = 0; q < 4; q++) {
            float4 a = *(const float4*)&sact[r * 1024 + q * 256 + 4 * lane];
            ss += dot4(a, a);
          }
          ss = wred(ss);
          if (lane == 0) sscale[r] = rsqrtf(ss);
        }
      }
      float acc[2][ROWS];
      if (w < 6) {
        #pragma unroll
        for (int c = 0; c < 2; c++)
          #pragma unroll
          for (int r = 0; r < ROWS; r++) acc[c][r] = 0.f;
        #pragma unroll
        for (int ch = 0; ch < 4; ch++)
          #pragma unroll
          for (int r = 0; r < ROWS; r++) {
            float4 a = *(const float4*)&sact[r * 1024 + ch * 256 + 4 * lane];
            fma4(acc[0][r], wbuf[ch], a);
            fma4(acc[1][r], wbuf[4 + ch], a);
          }
      }
      __syncthreads();              // sscale ready
      if (w < 6) {
        #pragma unroll
        for (int c = 0; c < 2; c++)
          #pragma unroll
          for (int r = 0; r < ROWS; r++) {
            float v = wred(acc[c][r]);
            if (lane == 0) {
              const int col = cbq + 2 * w + c;
              qkvb[r * 3072 + col] = v * sscale[r] + qb[col];
            }
          }
      }
    }
    gbar(&bars[(bi++) * 16]);

    // ============ attn (4 heads in-block) + O K-split, atomic += hs ============
    {
      float4 wbuf[2];
      #pragma unroll
      for (int c = 0; c < 2; c++)
        wbuf[c] = *(const float4*)&ow[(size_t)(cbo + 2 * w + c) * 1024 + ky * 256 + 4 * lane];

      const int bb = w >> 2, hw = w & 3, h = 4 * ky + hw;
      {
        const float ropeInv = powf(10000.f, -(float)(lane & 31) * (1.f / 32.f));
        float q[9], k[9], v[9];
        #pragma unroll
        for (int i = 0; i < 9; i++) {
          const float* base = qkvb + (size_t)(bb * 9 + i) * 3072;
          q[i] = base[h * 64 + lane];
          k[i] = base[1024 + h * 64 + lane];
          v[i] = base[2048 + h * 64 + lane];
        }
        #pragma unroll
        for (int i = 0; i < 9; i++) {
          const float ang = (float)i * ropeInv;
          float sn, cs;
          __sincosf(ang, &sn, &cs);
          const float sgn = (lane < 32) ? -sn : sn;
          const float rq = __shfl_xor(q[i], 32);
          const float rk = __shfl_xor(k[i], 32);
          q[i] = q[i] * cs + rq * sgn;
          k[i] = k[i] * cs + rk * sgn;
        }
        #pragma unroll
        for (int i = 0; i < 9; i++) {
          float sc[9];
          #pragma unroll
          for (int jj = 0; jj < 9; jj++) sc[jj] = wred(q[i] * k[jj]);
          float mx = sc[0];
          #pragma unroll
          for (int jj = 1; jj < 9; jj++) mx = fmaxf(mx, sc[jj]);
          float den = 0.f;
          #pragma unroll
          for (int jj = 0; jj < 9; jj++) { sc[jj] = __expf(sc[jj] - mx); den += sc[jj]; }
          float o = 0.f;
          #pragma unroll
          for (int jj = 0; jj < 9; jj++) o += sc[jj] * v[jj];
          sact[(bb * 9 + i) * 256 + hw * 64 + lane] = o / den;
        }
      }
      __syncthreads();
      float acc[2][ROWS];
      #pragma unroll
      for (int c = 0; c < 2; c++)
        #pragma unroll
        for (int r = 0; r < ROWS; r++) acc[c][r] = 0.f;
      #pragma unroll
      for (int r = 0; r < ROWS; r++) {
        float4 a = *(const float4*)&sact[r * 256 + 4 * lane];
        fma4(acc[0][r], wbuf[0], a);
        fma4(acc[1][r], wbuf[1], a);
      }
      #pragma unroll
      for (int c = 0; c < 2; c++)
        #pragma unroll
        for (int r = 0; r < ROWS; r++) {
          float v2 = wred(acc[c][r]);
          if (lane == 0) atomicAdd(&hs[r * 1024 + cbo + 2 * w + c], v2);
        }
    }
    gbar(&bars[(bi++) * 16]);

    // ============ gate_up + silu -> gub (gate -> LDS, then up) ============
    {
      const int c0 = cbg + 2 * w;
      float4 wbuf[8];
      #pragma unroll
      for (int j = 0; j < 2; j++)
        #pragma unroll
        for (int ch = 0; ch < 4; ch++)
          wbuf[j * 4 + ch] = *(const float4*)&gw[(size_t)(c0 + j) * 1024 + ch * 256 + 4 * lane];

      stage(hs, 1024, 0);
      __syncthreads();
      #pragma unroll
      for (int t = 0; t < 3; t++) {
        const int r = w + 8 * t;
        if (r < ROWS) {
          float ss = 0.f;
          #pragma unroll
          for (int q = 0; q < 4; q++) {
            float4 a = *(const float4*)&sact[r * 1024 + q * 256 + 4 * lane];
            ss += dot4(a, a);
          }
          ss = wred(ss);
          if (lane == 0) sscale[r] = rsqrtf(ss);
        }
      }
      __syncthreads();

      float acc[2][ROWS];
      // ---- gate ----
      #pragma unroll
      for (int c = 0; c < 2; c++)
        #pragma unroll
        for (int r = 0; r < ROWS; r++) acc[c][r] = 0.f;
      #pragma unroll
      for (int ch = 0; ch < 4; ch++)
        #pragma unroll
        for (int r = 0; r < ROWS; r++) {
          float4 a = *(const float4*)&sact[r * 1024 + ch * 256 + 4 * lane];
          fma4(acc[0][r], wbuf[ch], a);
          fma4(acc[1][r], wbuf[4 + ch], a);
        }
      #pragma unroll
      for (int c = 0; c < 2; c++)
        #pragma unroll
        for (int r = 0; r < ROWS; r++) {
          float g = wred(acc[c][r]);
          if (lane == 0) sredG[(2 * w + c) * ROWS + r] = g;  // same lane re-reads: no sync
        }
      // ---- up (reuse wbuf + acc) ----
      #pragma unroll
      for (int j = 0; j < 2; j++)
        #pragma unroll
        for (int ch = 0; ch < 4; ch++)
          wbuf[j * 4 + ch] = *(const float4*)&gw[(size_t)(4096 + c0 + j) * 1024 + ch * 256 + 4 * lane];
      #pragma unroll
      for (int c = 0; c < 2; c++)
        #pragma unroll
        for (int r = 0; r < ROWS; r++) acc[c][r] = 0.f;
      #pragma unroll
      for (int ch = 0; ch < 4; ch++)
        #pragma unroll
        for (int r = 0; r < ROWS; r++) {
          float4 a = *(const float4*)&sact[r * 1024 + ch * 256 + 4 * lane];
          fma4(acc[0][r], wbuf[ch], a);
          fma4(acc[1][r], wbuf[4 + ch], a);
        }
      #pragma unroll
      for (int c = 0; c < 2; c++)
        #pragma unroll
        for (int r = 0; r < ROWS; r++) {
          float u = wred(acc[c][r]);
          if (lane == 0) {
            const float s = sscale[r];
            const float g = sredG[(2 * w + c) * ROWS + r] * s;
            u *= s;
            gub[r * 4096 + c0 + c] = g / (1.f + __expf(-g)) * u;
          }
        }
    }
    gbar(&bars[(bi++) * 16]);

    // ============ down K-split, atomic += hs ============
    {
      float4 wbuf[8];
      #pragma unroll
      for (int c = 0; c < 2; c++)
        #pragma unroll
        for (int ch = 0; ch < 4; ch++)
          wbuf[c * 4 + ch] = *(const float4*)&dw[(size_t)(cbd + 2 * w + c) * 4096 + ky * 1024 + ch * 256 + 4 * lane];
      stage(gub, 4096, ky * 1024);
      __syncthreads();
      float acc[2][ROWS];
      #pragma unroll
      for (int c = 0; c < 2; c++)
        #pragma unroll
        for (int r = 0; r < ROWS; r++) acc[c][r] = 0.f;
      #pragma unroll
      for (int ch = 0; ch < 4; ch++)
        #pragma unroll
        for (int r = 0; r < ROWS; r++) {
          float4 a = *(const float4*)&sact[r * 1024 + ch * 256 + 4 * lane];
          fma4(acc[0][r], wbuf[ch], a);
          fma4(acc[1][r], wbuf[4 + ch], a);
        }
      #pragma unroll
      for (int c = 0; c < 2; c++)
        #pragma unroll
        for (int r = 0; r < ROWS; r++) {
          float v2 = wred(acc[c][r]);
          if (lane == 0) atomicAdd(&hs[r * 1024 + cbd + 2 * w + c], v2);
        }
    }
    gbar(&bars[(bi++) * 16]);
  }

  // ============ out_proj + CFG combine (block 0) ============
  if (b == 0) {
    for (int t4 = tid; t4 < 2048; t4 += 512) {
      const int r8 = t4 / 256;
      const int k4 = (t4 % 256) * 4;
      const int row = (r8 >> 2) * 9 + 5 + (r8 & 3);
      *(float4*)&sact[r8 * 1024 + k4] = *(const float4*)&hs[(size_t)row * 1024 + k4];
    }
    __syncthreads();
    {
      float ss = 0.f;
      #pragma unroll
      for (int qq = 0; qq < 4; qq++) {
        float4 a = *(const float4*)&sact[w * 1024 + 4 * lane + 256 * qq];
        ss += dot4(a, a);
      }
      ss = wred(ss);
      if (lane == 0) sA[w] = rsqrtf(ss);
    }
    __syncthreads();
    float outv;
    {
      const int r8 = tid & 7;
      const int c  = tid >> 3;
      float a0 = 0.f, a1 = 0.f;
      #pragma unroll 4
      for (int k4 = 0; k4 < 128; k4++) {
        a0 += dot4(*(const float4*)&sact[r8 * 1024 + 8 * k4],
                   *(const float4*)&op_w[(size_t)c * 1024 + 8 * k4]);
        a1 += dot4(*(const float4*)&sact[r8 * 1024 + 8 * k4 + 4],
                   *(const float4*)&op_w[(size_t)c * 1024 + 8 * k4 + 4]);
      }
      outv = (a0 + a1) * sA[r8] + op_b[c];
    }
    __syncthreads();
    {
      const int r8 = tid & 7;
      const int c  = tid >> 3;
      sact[r8 * 64 + c] = outv;
    }
    __syncthreads();
    float pos = 0.f, neg = 0.f, dd = 0.f, sq = 0.f;
    if (tid < 256) {
      pos = sact[tid]; neg = sact[256 + tid];
      dd = pos * neg; sq = neg * neg;
    }
    dd = wred(dd); sq = wred(sq);
    if (lane == 0) { sA[w] = dd; sB[w] = sq; }
    __syncthreads();
    if (tid < 256) {
      float dot = 0.f, sqs = 0.f;
      #pragma unroll
      for (int jj = 0; jj < 8; jj++) { dot += sA[jj]; sqs += sB[jj]; }
      const float guided = cfg[0] * pos + cfgm[0] * (dot / sqs) * neg;
      dout[tid] = random_[tid] + guided * dt[step[0]];
    }
  }
}

extern "C" void kernel_launch(void* const* d_in, const int* in_sizes, int n_in,
                              void* d_out, int out_size, void* d_ws, size_t ws_size,
                              hipStream_t stream)
{
  const int*   step    = (const int*)  d_in[0];
  const float* random_ = (const float*)d_in[1];
  const float* dit_h   = (const float*)d_in[2];
  const float* feat    = (const float*)d_in[3];
  const float* cfg     = (const float*)d_in[4];
  const float* cfgm    = (const float*)d_in[5];
  const float* t_emb   = (const float*)d_in[6];
  const float* dt      = (const float*)d_in[7];
  const float* in_w    = (const float*)d_in[8];
  const float* in_b    = (const float*)d_in[9];
  const float* qkv_w   = (const float*)d_in[10];
  const float* qkv_b   = (const float*)d_in[11];
  const float* o_w     = (const float*)d_in[12];
  const float* gu_w    = (const float*)d_in[13];
  const float* dn_w    = (const float*)d_in[14];
  const float* op_w    = (const float*)d_in[15];
  const float* op_b    = (const float*)d_in[16];

  unsigned* bars = (unsigned*)d_ws;                       // [0, 4096)
  float* hs   = (float*)((char*)d_ws + 4096);             // 18*1024
  float* qkvb = hs + ROWS * 1024;                         // 18*3072
  float* gub  = qkvb + ROWS * 3072;                       // 18*4096
  float* dout = (float*)d_out;

  hipMemsetAsync(d_ws, 0, 4096, stream);

  void* args[] = {
    (void*)&step, (void*)&random_, (void*)&dit_h, (void*)&feat, (void*)&cfg,
    (void*)&cfgm, (void*)&t_emb, (void*)&dt, (void*)&in_w, (void*)&in_b,
    (void*)&qkv_w, (void*)&qkv_b, (void*)&o_w, (void*)&gu_w, (void*)&dn_w,
    (void*)&op_w, (void*)&op_b, (void*)&bars,
    (void*)&hs, (void*)&qkvb, (void*)&gub, (void*)&dout
  };
  hipLaunchCooperativeKernel((void*)vox_persist, dim3(NBLK), dim3(512),
                             args, 0, stream);
}

// Round 7
// 2292.382 us; speedup vs baseline: 1.3685x; 1.1587x over previous
//
#include <hip/hip_runtime.h>

#define NBLK 256
#define ROWS 18

__device__ __forceinline__ float dot4(float4 a, float4 b){
  return fmaf(a.x,b.x, fmaf(a.y,b.y, fmaf(a.z,b.z, a.w*b.w)));
}
__device__ __forceinline__ void fma4(float& acc, float4 w, float4 a){
  acc = fmaf(w.x,a.x, fmaf(w.y,a.y, fmaf(w.z,a.z, fmaf(w.w,a.w, acc))));
}
__device__ __forceinline__ float wred(float v){
  #pragma unroll
  for (int m = 32; m >= 1; m >>= 1) v += __shfl_xor(v, m);
  return v;
}

// Tree barrier with epoch broadcast.
// Layout in bars[]: group counters at bars[g*16] (g=0..7, 64B apart),
// global counter at bars[128], epoch flag at bars[144].
// Arrival: 32 adds per group line -> 8 leader adds on global line ->
// block 0 publishes epoch. Spinners read ONLY the epoch line (single
// writer, stays clean -> no cross-XCD ping-pong).
__device__ __forceinline__ void gbar(unsigned* bars, int b, unsigned e){
  __syncthreads();
  if (threadIdx.x == 0) {
    __threadfence();   // release: write back this block's stores
    unsigned* grp = bars + (b >> 5) * 16;
    __hip_atomic_fetch_add(grp, 1u, __ATOMIC_RELAXED, __HIP_MEMORY_SCOPE_AGENT);
    if ((b & 31) == 0) {
      while (__hip_atomic_load(grp, __ATOMIC_RELAXED, __HIP_MEMORY_SCOPE_AGENT) < 32u * e)
        __builtin_amdgcn_s_sleep(2);
      __hip_atomic_fetch_add(bars + 128, 1u, __ATOMIC_RELAXED, __HIP_MEMORY_SCOPE_AGENT);
      if (b == 0) {
        while (__hip_atomic_load(bars + 128, __ATOMIC_RELAXED, __HIP_MEMORY_SCOPE_AGENT) < 8u * e)
          __builtin_amdgcn_s_sleep(2);
        __hip_atomic_store(bars + 144, e, __ATOMIC_RELAXED, __HIP_MEMORY_SCOPE_AGENT);
      }
    }
    while (__hip_atomic_load(bars + 144, __ATOMIC_RELAXED, __HIP_MEMORY_SCOPE_AGENT) < e)
      __builtin_amdgcn_s_sleep(2);
    __threadfence();   // acquire: invalidate stale cached lines
  }
  __syncthreads();
}

__global__ __launch_bounds__(512, 1)
void vox_persist(const int* __restrict__ step, const float* __restrict__ random_,
                 const float* __restrict__ dit_h, const float* __restrict__ feat,
                 const float* __restrict__ cfg, const float* __restrict__ cfgm,
                 const float* __restrict__ t_emb, const float* __restrict__ dt,
                 const float* __restrict__ in_w, const float* __restrict__ in_b,
                 const float* __restrict__ qkv_w, const float* __restrict__ qkv_b,
                 const float* __restrict__ o_w, const float* __restrict__ gu_w,
                 const float* __restrict__ dn_w, const float* __restrict__ op_w,
                 const float* __restrict__ op_b,
                 unsigned* __restrict__ bars,
                 float* __restrict__ hs, float* __restrict__ qkvb,
                 float* __restrict__ gub, float* __restrict__ dout)
{
  __shared__ float sact[ROWS * 1024];
  __shared__ float sredG[16 * ROWS];
  __shared__ float sscale[ROWS];
  __shared__ float sA[8], sB[8];

  const int b    = blockIdx.x;
  const int tid  = threadIdx.x;
  const int w    = tid >> 6;
  const int lane = tid & 63;
  unsigned e = 0;

  // ---------------- prep: hs[18][1024] ----------------
  if (b < 2) {
    const int c  = b * 512 + tid;
    const int st = step[0];
    const float tv = t_emb[(size_t)st * 1024 + c];
    hs[0 * 1024 + c] = dit_h[c] + tv;
    hs[9 * 1024 + c] = tv;
    #pragma unroll
    for (int p = 0; p < 4; p++) {
      hs[(1 + p)  * 1024 + c] = feat[(size_t)(p)     * 1024 + c];
      hs[(10 + p) * 1024 + c] = feat[(size_t)(4 + p) * 1024 + c];
    }
    #pragma unroll
    for (int p = 0; p < 4; p++) {
      float a = in_b[c];
      #pragma unroll
      for (int q4 = 0; q4 < 16; q4++) {
        float4 wv = *(const float4*)&in_w[(size_t)c * 64 + q4 * 4];
        float4 rv = *(const float4*)&random_[p * 64 + q4 * 4];
        a += dot4(wv, rv);
      }
      hs[(5 + p)  * 1024 + c] = a;
      hs[(14 + p) * 1024 + c] = a;
    }
  }

  // phase-static block mappings
  const int cbq = 12 * b;                   // QKV col base (waves 0-5, 2 cols)
  const int cg  = b & 63, ky = b >> 6;      // O / DOWN col-group & K-split
  const int cbo = 16 * cg;
  const int cbg = 16 * b;                   // GU col base (8 waves x 2 cols)
  const int cbd = 16 * cg;

  auto stage = [&](const float* src, int stride, int koff) {
    #pragma unroll 3
    for (int t = 0; t < 9; t++) {
      const int t4 = t * 512 + tid;
      const int r  = t4 >> 8;
      const int k4 = (t4 & 255) * 4;
      *(float4*)&sact[r * 1024 + k4] = *(const float4*)&src[(size_t)r * stride + koff + k4];
    }
  };

  gbar(bars, b, ++e);

  for (int l = 0; l < 8; l++) {
    const float* qw = qkv_w + (size_t)l * 3072 * 1024;
    const float* qb = qkv_b + (size_t)l * 3072;
    const float* ow = o_w   + (size_t)l * 1024 * 1024;
    const float* gw = gu_w  + (size_t)l * 8192 * 1024;
    const float* dw = dn_w  + (size_t)l * 1024 * 4096;

    // ============ QKV: qkvb = rms(hs) @ qw^T + qb ============
    {
      float4 wbuf[8];
      if (w < 6) {
        #pragma unroll
        for (int c = 0; c < 2; c++)
          #pragma unroll
          for (int ch = 0; ch < 4; ch++)
            wbuf[c * 4 + ch] = *(const float4*)&qw[(size_t)(cbq + 2 * w + c) * 1024 + ch * 256 + 4 * lane];
      }
      stage(hs, 1024, 0);
      __syncthreads();
      if (w >= 6) {                 // waves 6,7: rms of 9 rows each
        #pragma unroll
        for (int t = 0; t < 9; t++) {
          const int r = (w - 6) * 9 + t;
          float ss = 0.f;
          #pragma unroll
          for (int q = 0; q < 4; q++) {
            float4 a = *(const float4*)&sact[r * 1024 + q * 256 + 4 * lane];
            ss += dot4(a, a);
          }
          ss = wred(ss);
          if (lane == 0) sscale[r] = rsqrtf(ss);
        }
      }
      float acc[2][ROWS];
      if (w < 6) {
        #pragma unroll
        for (int c = 0; c < 2; c++)
          #pragma unroll
          for (int r = 0; r < ROWS; r++) acc[c][r] = 0.f;
        #pragma unroll
        for (int ch = 0; ch < 4; ch++)
          #pragma unroll
          for (int r = 0; r < ROWS; r++) {
            float4 a = *(const float4*)&sact[r * 1024 + ch * 256 + 4 * lane];
            fma4(acc[0][r], wbuf[ch], a);
            fma4(acc[1][r], wbuf[4 + ch], a);
          }
      }
      __syncthreads();              // sscale ready
      if (w < 6) {
        #pragma unroll
        for (int c = 0; c < 2; c++)
          #pragma unroll
          for (int r = 0; r < ROWS; r++) {
            float v = wred(acc[c][r]);
            if (lane == 0) {
              const int col = cbq + 2 * w + c;
              qkvb[r * 3072 + col] = v * sscale[r] + qb[col];
            }
          }
      }
    }
    gbar(bars, b, ++e);

    // ============ attn (4 heads in-block) + O K-split, atomic += hs ============
    {
      float4 wbuf[2];
      #pragma unroll
      for (int c = 0; c < 2; c++)
        wbuf[c] = *(const float4*)&ow[(size_t)(cbo + 2 * w + c) * 1024 + ky * 256 + 4 * lane];

      const int bb = w >> 2, hw = w & 3, h = 4 * ky + hw;
      {
        const float ropeInv = powf(10000.f, -(float)(lane & 31) * (1.f / 32.f));
        float q[9], k[9], v[9];
        #pragma unroll
        for (int i = 0; i < 9; i++) {
          const float* base = qkvb + (size_t)(bb * 9 + i) * 3072;
          q[i] = base[h * 64 + lane];
          k[i] = base[1024 + h * 64 + lane];
          v[i] = base[2048 + h * 64 + lane];
        }
        #pragma unroll
        for (int i = 0; i < 9; i++) {
          const float ang = (float)i * ropeInv;
          float sn, cs;
          __sincosf(ang, &sn, &cs);
          const float sgn = (lane < 32) ? -sn : sn;
          const float rq = __shfl_xor(q[i], 32);
          const float rk = __shfl_xor(k[i], 32);
          q[i] = q[i] * cs + rq * sgn;
          k[i] = k[i] * cs + rk * sgn;
        }
        #pragma unroll
        for (int i = 0; i < 9; i++) {
          float sc[9];
          #pragma unroll
          for (int jj = 0; jj < 9; jj++) sc[jj] = wred(q[i] * k[jj]);
          float mx = sc[0];
          #pragma unroll
          for (int jj = 1; jj < 9; jj++) mx = fmaxf(mx, sc[jj]);
          float den = 0.f;
          #pragma unroll
          for (int jj = 0; jj < 9; jj++) { sc[jj] = __expf(sc[jj] - mx); den += sc[jj]; }
          float o = 0.f;
          #pragma unroll
          for (int jj = 0; jj < 9; jj++) o += sc[jj] * v[jj];
          sact[(bb * 9 + i) * 256 + hw * 64 + lane] = o / den;
        }
      }
      __syncthreads();
      float acc[2][ROWS];
      #pragma unroll
      for (int c = 0; c < 2; c++)
        #pragma unroll
        for (int r = 0; r < ROWS; r++) acc[c][r] = 0.f;
      #pragma unroll
      for (int r = 0; r < ROWS; r++) {
        float4 a = *(const float4*)&sact[r * 256 + 4 * lane];
        fma4(acc[0][r], wbuf[0], a);
        fma4(acc[1][r], wbuf[1], a);
      }
      #pragma unroll
      for (int c = 0; c < 2; c++)
        #pragma unroll
        for (int r = 0; r < ROWS; r++) {
          float v2 = wred(acc[c][r]);
          if (lane == 0) atomicAdd(&hs[r * 1024 + cbo + 2 * w + c], v2);
        }
    }
    gbar(bars, b, ++e);

    // ============ gate_up + silu -> gub (gate -> LDS, then up) ============
    {
      const int c0 = cbg + 2 * w;
      float4 wbuf[8];
      #pragma unroll
      for (int j = 0; j < 2; j++)
        #pragma unroll
        for (int ch = 0; ch < 4; ch++)
          wbuf[j * 4 + ch] = *(const float4*)&gw[(size_t)(c0 + j) * 1024 + ch * 256 + 4 * lane];

      stage(hs, 1024, 0);
      __syncthreads();
      #pragma unroll
      for (int t = 0; t < 3; t++) {
        const int r = w + 8 * t;
        if (r < ROWS) {
          float ss = 0.f;
          #pragma unroll
          for (int q = 0; q < 4; q++) {
            float4 a = *(const float4*)&sact[r * 1024 + q * 256 + 4 * lane];
            ss += dot4(a, a);
          }
          ss = wred(ss);
          if (lane == 0) sscale[r] = rsqrtf(ss);
        }
      }
      __syncthreads();

      float acc[2][ROWS];
      // ---- gate ----
      #pragma unroll
      for (int c = 0; c < 2; c++)
        #pragma unroll
        for (int r = 0; r < ROWS; r++) acc[c][r] = 0.f;
      #pragma unroll
      for (int ch = 0; ch < 4; ch++)
        #pragma unroll
        for (int r = 0; r < ROWS; r++) {
          float4 a = *(const float4*)&sact[r * 1024 + ch * 256 + 4 * lane];
          fma4(acc[0][r], wbuf[ch], a);
          fma4(acc[1][r], wbuf[4 + ch], a);
        }
      #pragma unroll
      for (int c = 0; c < 2; c++)
        #pragma unroll
        for (int r = 0; r < ROWS; r++) {
          float g = wred(acc[c][r]);
          if (lane == 0) sredG[(2 * w + c) * ROWS + r] = g;  // same lane re-reads: no sync
        }
      // ---- up (reuse wbuf + acc) ----
      #pragma unroll
      for (int j = 0; j < 2; j++)
        #pragma unroll
        for (int ch = 0; ch < 4; ch++)
          wbuf[j * 4 + ch] = *(const float4*)&gw[(size_t)(4096 + c0 + j) * 1024 + ch * 256 + 4 * lane];
      #pragma unroll
      for (int c = 0; c < 2; c++)
        #pragma unroll
        for (int r = 0; r < ROWS; r++) acc[c][r] = 0.f;
      #pragma unroll
      for (int ch = 0; ch < 4; ch++)
        #pragma unroll
        for (int r = 0; r < ROWS; r++) {
          float4 a = *(const float4*)&sact[r * 1024 + ch * 256 + 4 * lane];
          fma4(acc[0][r], wbuf[ch], a);
          fma4(acc[1][r], wbuf[4 + ch], a);
        }
      #pragma unroll
      for (int c = 0; c < 2; c++)
        #pragma unroll
        for (int r = 0; r < ROWS; r++) {
          float u = wred(acc[c][r]);
          if (lane == 0) {
            const float s = sscale[r];
            const float g = sredG[(2 * w + c) * ROWS + r] * s;
            u *= s;
            gub[r * 4096 + c0 + c] = g / (1.f + __expf(-g)) * u;
          }
        }
    }
    gbar(bars, b, ++e);

    // ============ down K-split, atomic += hs ============
    {
      float4 wbuf[8];
      #pragma unroll
      for (int c = 0; c < 2; c++)
        #pragma unroll
        for (int ch = 0; ch < 4; ch++)
          wbuf[c * 4 + ch] = *(const float4*)&dw[(size_t)(cbd + 2 * w + c) * 4096 + ky * 1024 + ch * 256 + 4 * lane];
      stage(gub, 4096, ky * 1024);
      __syncthreads();
      float acc[2][ROWS];
      #pragma unroll
      for (int c = 0; c < 2; c++)
        #pragma unroll
        for (int r = 0; r < ROWS; r++) acc[c][r] = 0.f;
      #pragma unroll
      for (int ch = 0; ch < 4; ch++)
        #pragma unroll
        for (int r = 0; r < ROWS; r++) {
          float4 a = *(const float4*)&sact[r * 1024 + ch * 256 + 4 * lane];
          fma4(acc[0][r], wbuf[ch], a);
          fma4(acc[1][r], wbuf[4 + ch], a);
        }
      #pragma unroll
      for (int c = 0; c < 2; c++)
        #pragma unroll
        for (int r = 0; r < ROWS; r++) {
          float v2 = wred(acc[c][r]);
          if (lane == 0) atomicAdd(&hs[r * 1024 + cbd + 2 * w + c], v2);
        }
    }
    gbar(bars, b, ++e);
  }

  // ============ out_proj + CFG combine (block 0) ============
  if (b == 0) {
    for (int t4 = tid; t4 < 2048; t4 += 512) {
      const int r8 = t4 / 256;
      const int k4 = (t4 % 256) * 4;
      const int row = (r8 >> 2) * 9 + 5 + (r8 & 3);
      *(float4*)&sact[r8 * 1024 + k4] = *(const float4*)&hs[(size_t)row * 1024 + k4];
    }
    __syncthreads();
    {
      float ss = 0.f;
      #pragma unroll
      for (int qq = 0; qq < 4; qq++) {
        float4 a = *(const float4*)&sact[w * 1024 + 4 * lane + 256 * qq];
        ss += dot4(a, a);
      }
      ss = wred(ss);
      if (lane == 0) sA[w] = rsqrtf(ss);
    }
    __syncthreads();
    float outv;
    {
      const int r8 = tid & 7;
      const int c  = tid >> 3;
      float a0 = 0.f, a1 = 0.f;
      #pragma unroll 4
      for (int k4 = 0; k4 < 128; k4++) {
        a0 += dot4(*(const float4*)&sact[r8 * 1024 + 8 * k4],
                   *(const float4*)&op_w[(size_t)c * 1024 + 8 * k4]);
        a1 += dot4(*(const float4*)&sact[r8 * 1024 + 8 * k4 + 4],
                   *(const float4*)&op_w[(size_t)c * 1024 + 8 * k4 + 4]);
      }
      outv = (a0 + a1) * sA[r8] + op_b[c];
    }
    __syncthreads();
    {
      const int r8 = tid & 7;
      const int c  = tid >> 3;
      sact[r8 * 64 + c] = outv;
    }
    __syncthreads();
    float pos = 0.f, neg = 0.f, dd = 0.f, sq = 0.f;
    if (tid < 256) {
      pos = sact[tid]; neg = sact[256 + tid];
      dd = pos * neg; sq = neg * neg;
    }
    dd = wred(dd); sq = wred(sq);
    if (lane == 0) { sA[w] = dd; sB[w] = sq; }
    __syncthreads();
    if (tid < 256) {
      float dot = 0.f, sqs = 0.f;
      #pragma unroll
      for (int jj = 0; jj < 8; jj++) { dot += sA[jj]; sqs += sB[jj]; }
      const float guided = cfg[0] * pos + cfgm[0] * (dot / sqs) * neg;
      dout[tid] = random_[tid] + guided * dt[step[0]];
    }
  }
}

extern "C" void kernel_launch(void* const* d_in, const int* in_sizes, int n_in,
                              void* d_out, int out_size, void* d_ws, size_t ws_size,
                              hipStream_t stream)
{
  const int*   step    = (const int*)  d_in[0];
  const float* random_ = (const float*)d_in[1];
  const float* dit_h   = (const float*)d_in[2];
  const float* feat    = (const float*)d_in[3];
  const float* cfg     = (const float*)d_in[4];
  const float* cfgm    = (const float*)d_in[5];
  const float* t_emb   = (const float*)d_in[6];
  const float* dt      = (const float*)d_in[7];
  const float* in_w    = (const float*)d_in[8];
  const float* in_b    = (const float*)d_in[9];
  const float* qkv_w   = (const float*)d_in[10];
  const float* qkv_b   = (const float*)d_in[11];
  const float* o_w     = (const float*)d_in[12];
  const float* gu_w    = (const float*)d_in[13];
  const float* dn_w    = (const float*)d_in[14];
  const float* op_w    = (const float*)d_in[15];
  const float* op_b    = (const float*)d_in[16];

  unsigned* bars = (unsigned*)d_ws;                       // [0, 4096)
  float* hs   = (float*)((char*)d_ws + 4096);             // 18*1024
  float* qkvb = hs + ROWS * 1024;                         // 18*3072
  float* gub  = qkvb + ROWS * 3072;                       // 18*4096
  float* dout = (float*)d_out;

  hipMemsetAsync(d_ws, 0, 4096, stream);

  void* args[] = {
    (void*)&step, (void*)&random_, (void*)&dit_h, (void*)&feat, (void*)&cfg,
    (void*)&cfgm, (void*)&t_emb, (void*)&dt, (void*)&in_w, (void*)&in_b,
    (void*)&qkv_w, (void*)&qkv_b, (void*)&o_w, (void*)&gu_w, (void*)&dn_w,
    (void*)&op_w, (void*)&op_b, (void*)&bars,
    (void*)&hs, (void*)&qkvb, (void*)&gub, (void*)&dout
  };
  hipLaunchCooperativeKernel((void*)vox_persist, dim3(NBLK), dim3(512),
                             args, 0, stream);
}

// Round 8
// 2258.526 us; speedup vs baseline: 1.3890x; 1.0150x over previous
//
#include <hip/hip_runtime.h>

#define NBLK 256
#define ROWS 18

__device__ __forceinline__ float dot4(float4 a, float4 b){
  return fmaf(a.x,b.x, fmaf(a.y,b.y, fmaf(a.z,b.z, a.w*b.w)));
}
__device__ __forceinline__ void fma4(float& acc, float4 w, float4 a){
  acc = fmaf(w.x,a.x, fmaf(w.y,a.y, fmaf(w.z,a.z, fmaf(w.w,a.w, acc))));
}
__device__ __forceinline__ float wred(float v){
  #pragma unroll
  for (int m = 32; m >= 1; m >>= 1) v += __shfl_xor(v, m);
  return v;
}

// Agent-scope coherent accessors for the small cross-phase activation buffers.
// These bypass the (non-coherent) per-XCD L2 and complete at the coherence
// point, so NO cache-flushing fences are needed anywhere.
__device__ __forceinline__ float gld(const float* p){
  return __hip_atomic_load(p, __ATOMIC_RELAXED, __HIP_MEMORY_SCOPE_AGENT);
}
__device__ __forceinline__ void gst(float* p, float v){
  __hip_atomic_store(p, v, __ATOMIC_RELAXED, __HIP_MEMORY_SCOPE_AGENT);
}

// Tree barrier with epoch broadcast (proven R7), WITHOUT threadfences.
// Ordering argument: __syncthreads() drains every wave's vmcnt before
// thread 0 issues the arrival add, so all of this block's agent-scope
// stores/atomics have completed at the coherence point first. Readers
// see the epoch, then read via agent-scope loads -> fresh data.
__device__ __forceinline__ void gbar(unsigned* bars, int b, unsigned e){
  __syncthreads();
  if (threadIdx.x == 0) {
    unsigned* grp = bars + (b >> 5) * 16;
    __hip_atomic_fetch_add(grp, 1u, __ATOMIC_RELAXED, __HIP_MEMORY_SCOPE_AGENT);
    if ((b & 31) == 0) {
      while (__hip_atomic_load(grp, __ATOMIC_RELAXED, __HIP_MEMORY_SCOPE_AGENT) < 32u * e)
        __builtin_amdgcn_s_sleep(2);
      __hip_atomic_fetch_add(bars + 128, 1u, __ATOMIC_RELAXED, __HIP_MEMORY_SCOPE_AGENT);
      if (b == 0) {
        while (__hip_atomic_load(bars + 128, __ATOMIC_RELAXED, __HIP_MEMORY_SCOPE_AGENT) < 8u * e)
          __builtin_amdgcn_s_sleep(2);
        __hip_atomic_store(bars + 144, e, __ATOMIC_RELAXED, __HIP_MEMORY_SCOPE_AGENT);
      }
    }
    while (__hip_atomic_load(bars + 144, __ATOMIC_RELAXED, __HIP_MEMORY_SCOPE_AGENT) < e)
      __builtin_amdgcn_s_sleep(2);
  }
  __syncthreads();
}

__global__ __launch_bounds__(512, 1)
void vox_persist(const int* __restrict__ step, const float* __restrict__ random_,
                 const float* __restrict__ dit_h, const float* __restrict__ feat,
                 const float* __restrict__ cfg, const float* __restrict__ cfgm,
                 const float* __restrict__ t_emb, const float* __restrict__ dt,
                 const float* __restrict__ in_w, const float* __restrict__ in_b,
                 const float* __restrict__ qkv_w, const float* __restrict__ qkv_b,
                 const float* __restrict__ o_w, const float* __restrict__ gu_w,
                 const float* __restrict__ dn_w, const float* __restrict__ op_w,
                 const float* __restrict__ op_b,
                 unsigned* __restrict__ bars,
                 float* __restrict__ hs, float* __restrict__ qkvb,
                 float* __restrict__ gub, float* __restrict__ dout)
{
  __shared__ float sact[ROWS * 1024];
  __shared__ float sredG[16 * ROWS];
  __shared__ float sscale[ROWS];
  __shared__ float sA[8], sB[8];

  const int b    = blockIdx.x;
  const int tid  = threadIdx.x;
  const int w    = tid >> 6;
  const int lane = tid & 63;
  unsigned e = 0;

  // ---------------- prep: hs[18][1024] (coherent stores) ----------------
  if (b < 2) {
    const int c  = b * 512 + tid;
    const int st = step[0];
    const float tv = t_emb[(size_t)st * 1024 + c];
    gst(&hs[0 * 1024 + c], dit_h[c] + tv);
    gst(&hs[9 * 1024 + c], tv);
    #pragma unroll
    for (int p = 0; p < 4; p++) {
      gst(&hs[(1 + p)  * 1024 + c], feat[(size_t)(p)     * 1024 + c]);
      gst(&hs[(10 + p) * 1024 + c], feat[(size_t)(4 + p) * 1024 + c]);
    }
    #pragma unroll
    for (int p = 0; p < 4; p++) {
      float a = in_b[c];
      #pragma unroll
      for (int q4 = 0; q4 < 16; q4++) {
        float4 wv = *(const float4*)&in_w[(size_t)c * 64 + q4 * 4];
        float4 rv = *(const float4*)&random_[p * 64 + q4 * 4];
        a += dot4(wv, rv);
      }
      gst(&hs[(5 + p)  * 1024 + c], a);
      gst(&hs[(14 + p) * 1024 + c], a);
    }
  }

  // phase-static block mappings
  const int cbq = 12 * b;                   // QKV col base (waves 0-5, 2 cols)
  const int cg  = b & 63, ky = b >> 6;      // O / DOWN col-group & K-split
  const int cbo = 16 * cg;
  const int cbg = 16 * b;                   // GU col base (8 waves x 2 cols)
  const int cbd = 16 * cg;

  // stage 18x1024 slice into LDS via coherent 4B loads (coalesced)
  auto stage = [&](const float* src, int stride, int koff) {
    #pragma unroll 6
    for (int t = 0; t < 36; t++) {
      const int i = t * 512 + tid;
      const int r = i >> 10, k = i & 1023;
      sact[i] = gld(&src[(size_t)r * stride + koff + k]);
    }
  };

  gbar(bars, b, ++e);

  for (int l = 0; l < 8; l++) {
    const float* qw = qkv_w + (size_t)l * 3072 * 1024;
    const float* qb = qkv_b + (size_t)l * 3072;
    const float* ow = o_w   + (size_t)l * 1024 * 1024;
    const float* gw = gu_w  + (size_t)l * 8192 * 1024;
    const float* dw = dn_w  + (size_t)l * 1024 * 4096;

    // ============ QKV: qkvb = rms(hs) @ qw^T + qb ============
    {
      float4 wbuf[8];
      if (w < 6) {
        #pragma unroll
        for (int c = 0; c < 2; c++)
          #pragma unroll
          for (int ch = 0; ch < 4; ch++)
            wbuf[c * 4 + ch] = *(const float4*)&qw[(size_t)(cbq + 2 * w + c) * 1024 + ch * 256 + 4 * lane];
      }
      stage(hs, 1024, 0);
      __syncthreads();
      if (w >= 6) {                 // waves 6,7: rms of 9 rows each
        #pragma unroll
        for (int t = 0; t < 9; t++) {
          const int r = (w - 6) * 9 + t;
          float ss = 0.f;
          #pragma unroll
          for (int q = 0; q < 4; q++) {
            float4 a = *(const float4*)&sact[r * 1024 + q * 256 + 4 * lane];
            ss += dot4(a, a);
          }
          ss = wred(ss);
          if (lane == 0) sscale[r] = rsqrtf(ss);
        }
      }
      float acc[2][ROWS];
      if (w < 6) {
        #pragma unroll
        for (int c = 0; c < 2; c++)
          #pragma unroll
          for (int r = 0; r < ROWS; r++) acc[c][r] = 0.f;
        #pragma unroll
        for (int ch = 0; ch < 4; ch++)
          #pragma unroll
          for (int r = 0; r < ROWS; r++) {
            float4 a = *(const float4*)&sact[r * 1024 + ch * 256 + 4 * lane];
            fma4(acc[0][r], wbuf[ch], a);
            fma4(acc[1][r], wbuf[4 + ch], a);
          }
      }
      __syncthreads();              // sscale ready
      if (w < 6) {
        #pragma unroll
        for (int c = 0; c < 2; c++)
          #pragma unroll
          for (int r = 0; r < ROWS; r++) {
            float v = wred(acc[c][r]);
            if (lane == 0) {
              const int col = cbq + 2 * w + c;
              gst(&qkvb[r * 3072 + col], v * sscale[r] + qb[col]);
            }
          }
      }
    }
    gbar(bars, b, ++e);

    // ============ attn (4 heads in-block) + O K-split, atomic += hs ============
    {
      float4 wbuf[2];
      #pragma unroll
      for (int c = 0; c < 2; c++)
        wbuf[c] = *(const float4*)&ow[(size_t)(cbo + 2 * w + c) * 1024 + ky * 256 + 4 * lane];

      const int bb = w >> 2, hw = w & 3, h = 4 * ky + hw;
      {
        const float ropeInv = powf(10000.f, -(float)(lane & 31) * (1.f / 32.f));
        float q[9], k[9], v[9];
        #pragma unroll
        for (int i = 0; i < 9; i++) {
          const float* base = qkvb + (size_t)(bb * 9 + i) * 3072;
          q[i] = gld(&base[h * 64 + lane]);
          k[i] = gld(&base[1024 + h * 64 + lane]);
          v[i] = gld(&base[2048 + h * 64 + lane]);
        }
        #pragma unroll
        for (int i = 0; i < 9; i++) {
          const float ang = (float)i * ropeInv;
          float sn, cs;
          __sincosf(ang, &sn, &cs);
          const float sgn = (lane < 32) ? -sn : sn;
          const float rq = __shfl_xor(q[i], 32);
          const float rk = __shfl_xor(k[i], 32);
          q[i] = q[i] * cs + rq * sgn;
          k[i] = k[i] * cs + rk * sgn;
        }
        #pragma unroll
        for (int i = 0; i < 9; i++) {
          float sc[9];
          #pragma unroll
          for (int jj = 0; jj < 9; jj++) sc[jj] = wred(q[i] * k[jj]);
          float mx = sc[0];
          #pragma unroll
          for (int jj = 1; jj < 9; jj++) mx = fmaxf(mx, sc[jj]);
          float den = 0.f;
          #pragma unroll
          for (int jj = 0; jj < 9; jj++) { sc[jj] = __expf(sc[jj] - mx); den += sc[jj]; }
          float o = 0.f;
          #pragma unroll
          for (int jj = 0; jj < 9; jj++) o += sc[jj] * v[jj];
          sact[(bb * 9 + i) * 256 + hw * 64 + lane] = o / den;
        }
      }
      __syncthreads();
      float acc[2][ROWS];
      #pragma unroll
      for (int c = 0; c < 2; c++)
        #pragma unroll
        for (int r = 0; r < ROWS; r++) acc[c][r] = 0.f;
      #pragma unroll
      for (int r = 0; r < ROWS; r++) {
        float4 a = *(const float4*)&sact[r * 256 + 4 * lane];
        fma4(acc[0][r], wbuf[0], a);
        fma4(acc[1][r], wbuf[1], a);
      }
      #pragma unroll
      for (int c = 0; c < 2; c++)
        #pragma unroll
        for (int r = 0; r < ROWS; r++) {
          float v2 = wred(acc[c][r]);
          if (lane == 0) atomicAdd(&hs[r * 1024 + cbo + 2 * w + c], v2);
        }
    }
    gbar(bars, b, ++e);

    // ============ gate_up + silu -> gub (gate -> LDS, then up) ============
    {
      const int c0 = cbg + 2 * w;
      float4 wbuf[8];
      #pragma unroll
      for (int j = 0; j < 2; j++)
        #pragma unroll
        for (int ch = 0; ch < 4; ch++)
          wbuf[j * 4 + ch] = *(const float4*)&gw[(size_t)(c0 + j) * 1024 + ch * 256 + 4 * lane];

      stage(hs, 1024, 0);
      __syncthreads();
      #pragma unroll
      for (int t = 0; t < 3; t++) {
        const int r = w + 8 * t;
        if (r < ROWS) {
          float ss = 0.f;
          #pragma unroll
          for (int q = 0; q < 4; q++) {
            float4 a = *(const float4*)&sact[r * 1024 + q * 256 + 4 * lane];
            ss += dot4(a, a);
          }
          ss = wred(ss);
          if (lane == 0) sscale[r] = rsqrtf(ss);
        }
      }
      __syncthreads();

      float acc[2][ROWS];
      // ---- gate ----
      #pragma unroll
      for (int c = 0; c < 2; c++)
        #pragma unroll
        for (int r = 0; r < ROWS; r++) acc[c][r] = 0.f;
      #pragma unroll
      for (int ch = 0; ch < 4; ch++)
        #pragma unroll
        for (int r = 0; r < ROWS; r++) {
          float4 a = *(const float4*)&sact[r * 1024 + ch * 256 + 4 * lane];
          fma4(acc[0][r], wbuf[ch], a);
          fma4(acc[1][r], wbuf[4 + ch], a);
        }
      #pragma unroll
      for (int c = 0; c < 2; c++)
        #pragma unroll
        for (int r = 0; r < ROWS; r++) {
          float g = wred(acc[c][r]);
          if (lane == 0) sredG[(2 * w + c) * ROWS + r] = g;  // same lane re-reads: no sync
        }
      // ---- up (reuse wbuf + acc) ----
      #pragma unroll
      for (int j = 0; j < 2; j++)
        #pragma unroll
        for (int ch = 0; ch < 4; ch++)
          wbuf[j * 4 + ch] = *(const float4*)&gw[(size_t)(4096 + c0 + j) * 1024 + ch * 256 + 4 * lane];
      #pragma unroll
      for (int c = 0; c < 2; c++)
        #pragma unroll
        for (int r = 0; r < ROWS; r++) acc[c][r] = 0.f;
      #pragma unroll
      for (int ch = 0; ch < 4; ch++)
        #pragma unroll
        for (int r = 0; r < ROWS; r++) {
          float4 a = *(const float4*)&sact[r * 1024 + ch * 256 + 4 * lane];
          fma4(acc[0][r], wbuf[ch], a);
          fma4(acc[1][r], wbuf[4 + ch], a);
        }
      #pragma unroll
      for (int c = 0; c < 2; c++)
        #pragma unroll
        for (int r = 0; r < ROWS; r++) {
          float u = wred(acc[c][r]);
          if (lane == 0) {
            const float s = sscale[r];
            const float g = sredG[(2 * w + c) * ROWS + r] * s;
            u *= s;
            gst(&gub[r * 4096 + c0 + c], g / (1.f + __expf(-g)) * u);
          }
        }
    }
    gbar(bars, b, ++e);

    // ============ down K-split, atomic += hs ============
    {
      float4 wbuf[8];
      #pragma unroll
      for (int c = 0; c < 2; c++)
        #pragma unroll
        for (int ch = 0; ch < 4; ch++)
          wbuf[c * 4 + ch] = *(const float4*)&dw[(size_t)(cbd + 2 * w + c) * 4096 + ky * 1024 + ch * 256 + 4 * lane];
      stage(gub, 4096, ky * 1024);
      __syncthreads();
      float acc[2][ROWS];
      #pragma unroll
      for (int c = 0; c < 2; c++)
        #pragma unroll
        for (int r = 0; r < ROWS; r++) acc[c][r] = 0.f;
      #pragma unroll
      for (int ch = 0; ch < 4; ch++)
        #pragma unroll
        for (int r = 0; r < ROWS; r++) {
          float4 a = *(const float4*)&sact[r * 1024 + ch * 256 + 4 * lane];
          fma4(acc[0][r], wbuf[ch], a);
          fma4(acc[1][r], wbuf[4 + ch], a);
        }
      #pragma unroll
      for (int c = 0; c < 2; c++)
        #pragma unroll
        for (int r = 0; r < ROWS; r++) {
          float v2 = wred(acc[c][r]);
          if (lane == 0) atomicAdd(&hs[r * 1024 + cbd + 2 * w + c], v2);
        }
    }
    gbar(bars, b, ++e);
  }

  // ============ out_proj + CFG combine (block 0) ============
  if (b == 0) {
    for (int i = tid; i < 8192; i += 512) {
      const int r8 = i >> 10, k = i & 1023;
      const int row = (r8 >> 2) * 9 + 5 + (r8 & 3);
      sact[r8 * 1024 + k] = gld(&hs[(size_t)row * 1024 + k]);
    }
    __syncthreads();
    {
      float ss = 0.f;
      #pragma unroll
      for (int qq = 0; qq < 4; qq++) {
        float4 a = *(const float4*)&sact[w * 1024 + 4 * lane + 256 * qq];
        ss += dot4(a, a);
      }
      ss = wred(ss);
      if (lane == 0) sA[w] = rsqrtf(ss);
    }
    __syncthreads();
    float outv;
    {
      const int r8 = tid & 7;
      const int c  = tid >> 3;
      float a0 = 0.f, a1 = 0.f;
      #pragma unroll 4
      for (int k4 = 0; k4 < 128; k4++) {
        a0 += dot4(*(const float4*)&sact[r8 * 1024 + 8 * k4],
                   *(const float4*)&op_w[(size_t)c * 1024 + 8 * k4]);
        a1 += dot4(*(const float4*)&sact[r8 * 1024 + 8 * k4 + 4],
                   *(const float4*)&op_w[(size_t)c * 1024 + 8 * k4 + 4]);
      }
      outv = (a0 + a1) * sA[r8] + op_b[c];
    }
    __syncthreads();
    {
      const int r8 = tid & 7;
      const int c  = tid >> 3;
      sact[r8 * 64 + c] = outv;
    }
    __syncthreads();
    float pos = 0.f, neg = 0.f, dd = 0.f, sq = 0.f;
    if (tid < 256) {
      pos = sact[tid]; neg = sact[256 + tid];
      dd = pos * neg; sq = neg * neg;
    }
    dd = wred(dd); sq = wred(sq);
    if (lane == 0) { sA[w] = dd; sB[w] = sq; }
    __syncthreads();
    if (tid < 256) {
      float dot = 0.f, sqs = 0.f;
      #pragma unroll
      for (int jj = 0; jj < 8; jj++) { dot += sA[jj]; sqs += sB[jj]; }
      const float guided = cfg[0] * pos + cfgm[0] * (dot / sqs) * neg;
      dout[tid] = random_[tid] + guided * dt[step[0]];
    }
  }
}

extern "C" void kernel_launch(void* const* d_in, const int* in_sizes, int n_in,
                              void* d_out, int out_size, void* d_ws, size_t ws_size,
                              hipStream_t stream)
{
  const int*   step    = (const int*)  d_in[0];
  const float* random_ = (const float*)d_in[1];
  const float* dit_h   = (const float*)d_in[2];
  const float* feat    = (const float*)d_in[3];
  const float* cfg     = (const float*)d_in[4];
  const float* cfgm    = (const float*)d_in[5];
  const float* t_emb   = (const float*)d_in[6];
  const float* dt      = (const float*)d_in[7];
  const float* in_w    = (const float*)d_in[8];
  const float* in_b    = (const float*)d_in[9];
  const float* qkv_w   = (const float*)d_in[10];
  const float* qkv_b   = (const float*)d_in[11];
  const float* o_w     = (const float*)d_in[12];
  const float* gu_w    = (const float*)d_in[13];
  const float* dn_w    = (const float*)d_in[14];
  const float* op_w    = (const float*)d_in[15];
  const float* op_b    = (const float*)d_in[16];

  unsigned* bars = (unsigned*)d_ws;                       // [0, 4096)
  float* hs   = (float*)((char*)d_ws + 4096);             // 18*1024
  float* qkvb = hs + ROWS * 1024;                         // 18*3072
  float* gub  = qkvb + ROWS * 3072;                       // 18*4096
  float* dout = (float*)d_out;

  hipMemsetAsync(d_ws, 0, 4096, stream);

  void* args[] = {
    (void*)&step, (void*)&random_, (void*)&dit_h, (void*)&feat, (void*)&cfg,
    (void*)&cfgm, (void*)&t_emb, (void*)&dt, (void*)&in_w, (void*)&in_b,
    (void*)&qkv_w, (void*)&qkv_b, (void*)&o_w, (void*)&gu_w, (void*)&dn_w,
    (void*)&op_w, (void*)&op_b, (void*)&bars,
    (void*)&hs, (void*)&qkvb, (void*)&gub, (void*)&dout
  };
  hipLaunchCooperativeKernel((void*)vox_persist, dim3(NBLK), dim3(512),
                             args, 0, stream);
}